// Round 6
// baseline (1374.660 us; speedup 1.0000x reference)
//
#include <hip/hip_runtime.h>
#include <hip/hip_bf16.h>
#include <cstdint>

#define B_SZ 1000
#define D_SZ 512
#define N_SZ 100000
#define F_SZ 50
#define NEGV -1000000.0f

// ---- 256x256 main tile geometry ----
#define BM2 256
#define NT_N2 391            // 391*256 = 100096
#define NT_B2 4              // 1024/256
#define G2 (NT_B2 * NT_N2)   // 1564 blocks
#define CAP2 160             // avg entries/bin ~32.6

#define T_OFF 0
#define CNT_OFF 4096
#define ENT_OFF 32768            // entries: 1564*160*4B = 1.0 MB (< 2MB gap)
#define QB_OFF  0x200000         // qb2: 4*8*8*256*16B = 1 MB (2 MB region)
#define RT_OFF  0x400000         // rhsT2: 391 * 256KB = 102.5 MB
#define RT_ROWS 100096

typedef __bf16 bf16x8 __attribute__((ext_vector_type(8)));
typedef float f32x4 __attribute__((ext_vector_type(4)));

__device__ __forceinline__ void gl_lds16(const void* g, void* l){
  __builtin_amdgcn_global_load_lds(
      (const __attribute__((address_space(1))) unsigned int*)g,
      (__attribute__((address_space(3))) unsigned int*)l, 16, 0, 0);
}

// ---------------- zero t/cnt regions (ws poisoned 0xAA each call) ----------
__global__ void zero_ws(int* p){ p[blockIdx.x * 256 + threadIdx.x] = 0; }

// ---------------- q f32 [1000][512] -> qb2 tiled bf16 ----------------------
// qb2 layout: [mt 4][kt 8][kq 8][row 256][8 bf16]  (LDS-tile order, pads 0)
__global__ void cvtq_kernel(const float* __restrict__ q, __bf16* __restrict__ qb){
  int g = blockIdx.x * 256 + threadIdx.x;
  int row = g >> 6;                 // 0..1023
  int k0 = (g & 63) * 8;
  float4 v0 = make_float4(0.f,0.f,0.f,0.f), v1 = v0;
  if(row < B_SZ){
    v0 = *(const float4*)(q + (size_t)row * D_SZ + k0);
    v1 = *(const float4*)(q + (size_t)row * D_SZ + k0 + 4);
  }
  bf16x8 w = { (__bf16)v0.x,(__bf16)v0.y,(__bf16)v0.z,(__bf16)v0.w,
               (__bf16)v1.x,(__bf16)v1.y,(__bf16)v1.z,(__bf16)v1.w };
  int mt = row >> 8, r = row & 255;
  int kt = k0 >> 6, kq = (k0 >> 3) & 7;
  *(bf16x8*)(qb + ((size_t)(mt*8 + kt)*8 + kq) * 2048 + (size_t)r * 8) = w;
}

// ---------------- rhs f32 [512][100000] -> rhsT2 tiled bf16 ----------------
// rhsT2 layout: [nt 391][kt 8][kq 8][row 256][8 bf16]
__global__ __launch_bounds__(256)
void tconv_kernel(const float* __restrict__ rhs, __bf16* __restrict__ rhsT){
  __shared__ float tile[64][65];
  const int tn = blockIdx.x;           // 0..1563
  const int tk = blockIdx.y;           // 0..7 (one k-tile per block)
  const int tid = threadIdx.x;
  const int n0 = tn * 64, k0 = tk * 64;
  // read phase: coalesced along n
  {
    const int nc = (tid & 15) * 4;
    const int kr0 = tid >> 4;          // 0..15
    #pragma unroll
    for(int i = 0; i < 4; i++){
      int kr = kr0 + i * 16;
      int n = n0 + nc;
      float4 v = (n < N_SZ) ? *(const float4*)(rhs + (size_t)(k0 + kr) * N_SZ + n)
                            : make_float4(0.f,0.f,0.f,0.f);
      tile[kr][nc+0] = v.x; tile[kr][nc+1] = v.y;
      tile[kr][nc+2] = v.z; tile[kr][nc+3] = v.w;
    }
  }
  __syncthreads();
  // write phase: lane = n (perfectly coalesced 1KB per kq region)
  {
    const int nl = tid & 63;
    const int kc = (tid >> 6) * 16;    // 0,16,32,48
    float a[16];
    #pragma unroll
    for(int j = 0; j < 16; j++) a[j] = tile[kc + j][nl];
    bf16x8 w0, w1;
    #pragma unroll
    for(int j = 0; j < 8; j++){ w0[j] = (__bf16)a[j]; w1[j] = (__bf16)a[8 + j]; }
    const int ng = n0 + nl;
    const int nt = ng >> 8, r = ng & 255;
    const int kq0 = kc >> 3;           // 0,2,4,6
    __bf16* dst = rhsT + ((size_t)(nt*8 + tk)*8 + kq0) * 2048 + (size_t)r * 8;
    *(bf16x8*)dst = w0;
    *(bf16x8*)(dst + 2048) = w1;       // kq0+1
  }
}

// ---------------- t[b] = q[b] . rhs[:, target[b]] (f32 exact) --------------
__global__ void t_kernel(const float* __restrict__ q, const float* __restrict__ rhs,
                         const int* __restrict__ target, float* __restrict__ t){
  int b = blockIdx.x;
  int tid = threadIdx.x;
  int tj = target[b];
  const float* qb = q + (size_t)b * D_SZ;
  float p = qb[tid] * rhs[(size_t)tid * N_SZ + tj]
          + qb[tid + 256] * rhs[(size_t)(tid + 256) * N_SZ + tj];
  for(int off = 32; off; off >>= 1) p += __shfl_down(p, off);
  __shared__ float red[4];
  if((tid & 63) == 0) red[tid >> 6] = p;
  __syncthreads();
  if(tid == 0) t[b] = red[0] + red[1] + red[2] + red[3];
}

// ---------------- dedupe filter∪target, bin into owning 256x256 tile -------
// Wave-parallel: shuffle-based first-occurrence test, no scratch arrays.
__global__ __launch_bounds__(64)
void prep_kernel(const int* __restrict__ filt, const int* __restrict__ target,
                 const float* __restrict__ t, int* __restrict__ cnt,
                 unsigned* __restrict__ entries, float* __restrict__ out){
  const int b = blockIdx.x;
  const int lane = threadIdx.x;      // 64 lanes, one wave
  int v = 0x7fffffff;
  if(lane < F_SZ) v = filt[b * F_SZ + lane];
  else if(lane == F_SZ) v = target[b];
  const bool active = lane <= F_SZ;
  bool first = active;
  #pragma unroll 1
  for(int k = 0; k < F_SZ; k++){     // lane>k duplicates of lane k are not-first
    int o = __shfl(v, k);
    if(active && k < lane && o == v) first = false;
  }
  if(first){
    int bid = (b >> 8) * NT_N2 + (v >> 8);
    int pos = atomicAdd(&cnt[bid], 1);
    if(pos < CAP2)
      entries[(size_t)bid * CAP2 + pos] = (unsigned)(((b & 255) << 8) | (v & 255));
  }
  int nuniq = (int)__popcll(__ballot(first));
  if(lane == 0){
    float tb = t[b];
    out[b] = 1.0f + ((NEGV >= tb) ? (float)nuniq : 0.0f);
  }
}

// ---------------- fused 256x256 MFMA GEMM + rank count ---------------------
// BK=32, 16 K-tiles, 8 waves (2M x 4N), 2-barrier loop, counted vmcnt(4).
// LDS: 2x(16KB A + 16KB B) + ~11KB tables = ~75KB -> 2 BLOCKS/CU.
// Rationale (R5 post-mortem): per K-tile, LDS-read pipe (~192KB/CU @85B/cy)
// and MFMA pipe (~2.5kcy) are EQUAL; barrier-locked phases at 1 block/CU
// serialize them. Two independent blocks/CU overlap one block's LDS/barrier
// windows with the other's MFMA bursts (m114 implicit-TLP), no explicit
// pipelining needed. Per-K-tile per wave: 12 ds_read_b128 (data minimum:
// A 8, B 4 - no re-reads) + 32 MFMA.
__global__ __launch_bounds__(512, 4)
void main_kernel(const __bf16* __restrict__ rhsT, const __bf16* __restrict__ qb,
                 const float* __restrict__ t, const int* __restrict__ cnt,
                 const unsigned* __restrict__ entries, float* __restrict__ out){
  __shared__ __attribute__((aligned(16))) __bf16 A2[2][8192];  // 32 KB
  __shared__ __attribute__((aligned(16))) __bf16 B2[2][8192];  // 32 KB
  __shared__ float tl[256];
  __shared__ unsigned lent[CAP2];
  __shared__ unsigned bm[2048];      // 256 rows x 256 cols bit map (8 KB)
  __shared__ int rowc[256];
  __shared__ int lcnt_s;

  // ---- bijective XCD swizzle (nwg=1564 = 8*195+4): 4 consecutive wg
  // (the 4 tile_b sharers of one B-strip) land on one XCD.
  const int h = blockIdx.x;
  const int xcd = h & 7, slot = h >> 3;
  const int wg = (xcd < 4 ? xcd * 196 : 784 + (xcd - 4) * 195) + slot;
  const int tile_n = wg >> 2;        // 0..390
  const int tile_b = wg & 3;         // 0..3
  const int bid = tile_b * NT_N2 + tile_n;
  const int tid = threadIdx.x;
  const int n0 = tile_n * BM2;
  const int b0 = tile_b * BM2;

  if(tid < 256){ int b = b0 + tid; tl[tid] = (b < B_SZ) ? t[b] : 0.f; rowc[tid] = 0; }
  if(tid < CAP2) lent[tid] = entries[(size_t)bid * CAP2 + tid];
  if(tid == 0){ int c = cnt[bid]; lcnt_s = (c > CAP2) ? CAP2 : c; }
  bm[tid] = 0; bm[tid + 512] = 0; bm[tid + 1024] = 0; bm[tid + 1536] = 0;

  const int wave = tid >> 6, lane = tid & 63;
  const int quad = lane >> 4, l15 = lane & 15;
  const int wm = wave >> 2, wn = wave & 3;   // 2 x 4 wave grid

  // staging source pointers (linear copy: global layout == LDS layout).
  // BK=32 tile kt covers k-octets 4kt..4kt+3, contiguous in the [kt64][kq]
  // global layout: offset kt * 4*256*8 = kt * 8192 elems.
  const __bf16* pA = qb   + (size_t)tile_b * 131072 + (size_t)tid * 8;
  const __bf16* pB = rhsT + (size_t)tile_n * 131072 + (size_t)tid * 8;

  f32x4 acc[8][4];
  #pragma unroll
  for(int i = 0; i < 8; i++)
    #pragma unroll
    for(int j = 0; j < 4; j++)
      acc[i][j] = (f32x4){0.f, 0.f, 0.f, 0.f};

  __syncthreads();                 // tables resident; drains table-load vmcnt
  {                                // mark filter bitmap (LDS atomics)
    int lc = lcnt_s;
    if(tid < lc){
      unsigned en = lent[tid];
      unsigned row = en >> 8, col = en & 255;
      atomicOr(&bm[row * 8 + (col >> 5)], 1u << (col & 31));
    }
  }
  // ---- prologue: stage K-tile 0 into buffer 0 (4 loads/thread)
  gl_lds16(pA,        &A2[0][tid * 8]);
  gl_lds16(pA + 4096, &A2[0][4096 + tid * 8]);
  gl_lds16(pB,        &B2[0][tid * 8]);
  gl_lds16(pB + 4096, &B2[0][4096 + tid * 8]);
  pA += 8192; pB += 8192;
  asm volatile("s_waitcnt vmcnt(0)" ::: "memory");
  __builtin_amdgcn_s_barrier();
  asm volatile("" ::: "memory");

  #pragma unroll 1
  for(int kt = 0; kt < 16; kt++){
    const int cur = kt & 1, nxt = cur ^ 1;
    const __bf16* baA = &A2[cur][quad * 2048 + (size_t)(wm * 128 + l15) * 8];
    const __bf16* baB = &B2[cur][quad * 2048 + (size_t)(wn * 64  + l15) * 8];

    if(kt < 15){
      // issue next tile's 4 loads; vmcnt(4) waits only for OLDER loads
      // (i.e. tile kt's) -> next-tile loads stay in flight across compute.
      gl_lds16(pA,        &A2[nxt][tid * 8]);
      gl_lds16(pA + 4096, &A2[nxt][4096 + tid * 8]);
      gl_lds16(pB,        &B2[nxt][tid * 8]);
      gl_lds16(pB + 4096, &B2[nxt][4096 + tid * 8]);
      pA += 8192; pB += 8192;
      asm volatile("s_waitcnt vmcnt(4)" ::: "memory");
    } else {
      asm volatile("s_waitcnt vmcnt(0)" ::: "memory");
    }
    __builtin_amdgcn_s_barrier();        // tile kt resident for all waves
    asm volatile("" ::: "memory");

    bf16x8 a8[8], b4[4];
    #pragma unroll
    for(int i = 0; i < 8; i++) a8[i] = *(const bf16x8*)(baA + i * 128);
    #pragma unroll
    for(int j = 0; j < 4; j++) b4[j] = *(const bf16x8*)(baB + j * 128);
    __builtin_amdgcn_s_setprio(1);
    #pragma unroll
    for(int i = 0; i < 8; i++)
      #pragma unroll
      for(int j = 0; j < 4; j++)
        acc[i][j] = __builtin_amdgcn_mfma_f32_16x16x32_bf16(a8[i], b4[j], acc[i][j], 0, 0, 0);
    __builtin_amdgcn_s_setprio(0);

    // my reads of buf[cur] done before the barrier -> next iteration's
    // staging (which targets buf[cur] two tiles later) can't race.
    asm volatile("s_waitcnt lgkmcnt(0)" ::: "memory");
    __builtin_amdgcn_s_barrier();
    asm volatile("" ::: "memory");
  }

  // ---- epilogue: count s >= t_row, excluding bitmap-marked filter entries --
  // C/D layout: col = l15 (+16j), row = quad*4 + r (+16i) [verified mapping]
  #pragma unroll
  for(int i = 0; i < 8; i++){
    #pragma unroll
    for(int r = 0; r < 4; r++){
      const int row = wm*128 + i*16 + quad*4 + r;
      const float trow = tl[row];
      const unsigned w01 = bm[row * 8 + wn * 2];
      const unsigned w23 = bm[row * 8 + wn * 2 + 1];
      int c = 0;
      bool ge[4];
      #pragma unroll
      for(int j = 0; j < 4; j++){
        int ncol = n0 + wn*64 + j*16 + l15;
        ge[j] = (ncol < N_SZ) && (acc[i][j][r] >= trow);
        c += ge[j] ? 1 : 0;
      }
      if(w01 | w23){                      // rare
        #pragma unroll
        for(int j = 0; j < 4; j++){
          unsigned w = (j < 2) ? w01 : w23;
          if(((w >> ((j & 1) * 16 + l15)) & 1u) && ge[j]) c--;
        }
      }
      c += __shfl_xor(c, 1);
      c += __shfl_xor(c, 2);
      c += __shfl_xor(c, 4);
      c += __shfl_xor(c, 8);
      if(l15 == 0) atomicAdd(&rowc[row], c);
    }
  }
  __syncthreads();
  if(tid < 256){
    int bg = b0 + tid, c = rowc[tid];
    if(bg < B_SZ && c) atomicAdd(&out[bg], (float)c);
  }
}

// ---------------- correctness fallback (small ws): plain f32 counting ------
__global__ __launch_bounds__(256)
void fallback_kernel(const float* __restrict__ q, const float* __restrict__ rhs,
                     const int* __restrict__ filt, const int* __restrict__ target,
                     const float* __restrict__ t, float* __restrict__ out){
  const int b = blockIdx.x;
  const int tid = threadIdx.x;
  __shared__ float qs[D_SZ];
  __shared__ int fs[F_SZ + 1];
  __shared__ float tbs;
  qs[tid] = q[(size_t)b * D_SZ + tid];
  qs[tid + 256] = q[(size_t)b * D_SZ + tid + 256];
  if(tid < F_SZ) fs[tid] = filt[b * F_SZ + tid];
  if(tid == F_SZ) fs[tid] = target[b];
  if(tid == 0) tbs = t[b];
  __syncthreads();
  const float tb = tbs;
  int c = 0;
  const int nend = (blockIdx.y + 1) * 2048 < N_SZ ? (blockIdx.y + 1) * 2048 : N_SZ;
  for(int n = blockIdx.y * 2048 + tid; n < nend; n += 256){
    float s = 0.f;
    for(int k = 0; k < D_SZ; k++) s += qs[k] * rhs[(size_t)k * N_SZ + n];
    if(s >= tb){
      bool m = false;
      for(int i = 0; i <= F_SZ; i++) if(fs[i] == n){ m = true; break; }
      if(!m) c++;
    }
  }
  for(int off = 32; off; off >>= 1) c += __shfl_down(c, off);
  __shared__ int red[4];
  if((tid & 63) == 0) red[tid >> 6] = c;
  __syncthreads();
  if(tid == 0){
    int s = red[0] + red[1] + red[2] + red[3];
    if(s) atomicAdd(&out[b], (float)s);
  }
}

extern "C" void kernel_launch(void* const* d_in, const int* in_sizes, int n_in,
                              void* d_out, int out_size, void* d_ws, size_t ws_size,
                              hipStream_t stream){
  const float* q    = (const float*)d_in[0];
  const float* rhs  = (const float*)d_in[1];
  const int* filt   = (const int*)d_in[2];
  const int* target = (const int*)d_in[3];
  float* out = (float*)d_out;
  char* ws = (char*)d_ws;
  float* t          = (float*)(ws + T_OFF);
  int* cnt          = (int*)(ws + CNT_OFF);
  unsigned* entries = (unsigned*)(ws + ENT_OFF);
  __bf16* qb        = (__bf16*)(ws + QB_OFF);
  __bf16* rhsT      = (__bf16*)(ws + RT_OFF);

  const size_t need = (size_t)RT_OFF + (size_t)RT_ROWS * D_SZ * 2;   // ~106.7 MB
  const bool big = ws_size >= need;

  zero_ws<<<32, 256, 0, stream>>>((int*)ws);
  t_kernel<<<B_SZ, 256, 0, stream>>>(q, rhs, target, t);
  prep_kernel<<<B_SZ, 64, 0, stream>>>(filt, target, t, cnt, entries, out);
  if(big){
    cvtq_kernel<<<256, 256, 0, stream>>>(q, qb);
    tconv_kernel<<<dim3(RT_ROWS / 64, 8), 256, 0, stream>>>(rhs, rhsT);
    main_kernel<<<G2, 512, 0, stream>>>(rhsT, qb, t, cnt, entries, out);
  } else {
    fallback_kernel<<<dim3(B_SZ, 49), 256, 0, stream>>>(q, rhs, filt, target, t, out);
  }
}

// Round 7
// 842.062 us; speedup vs baseline: 1.6325x; 1.6325x over previous
//
#include <hip/hip_runtime.h>
#include <hip/hip_bf16.h>
#include <cstdint>

#define B_SZ 1000
#define D_SZ 512
#define N_SZ 100000
#define F_SZ 50
#define NEGV -1000000.0f

// ---- 256x256 main tile geometry ----
#define BM2 256
#define NT_N2 391            // 391*256 = 100096
#define NT_B2 4              // 1024/256
#define G2 (NT_B2 * NT_N2)   // 1564 blocks
#define CAP2 160             // avg entries/bin ~32.6

#define T_OFF 0
#define CNT_OFF 4096
#define ENT_OFF 32768            // entries: 1564*160*4B = 1.0 MB (< 2MB gap)
#define QB_OFF  0x200000         // qb2: 4*8*8*256*16B = 1 MB (2 MB region)
#define RT_OFF  0x400000         // rhsT2: 391 * 256KB = 102.5 MB
#define RT_ROWS 100096

typedef __bf16 bf16x8 __attribute__((ext_vector_type(8)));
typedef float f32x4 __attribute__((ext_vector_type(4)));

__device__ __forceinline__ void gl_lds16(const void* g, void* l){
  __builtin_amdgcn_global_load_lds(
      (const __attribute__((address_space(1))) unsigned int*)g,
      (__attribute__((address_space(3))) unsigned int*)l, 16, 0, 0);
}

// ---------------- zero t/cnt regions (ws poisoned 0xAA each call) ----------
__global__ void zero_ws(int* p){ p[blockIdx.x * 256 + threadIdx.x] = 0; }

// ---------------- q f32 [1000][512] -> qb2 tiled bf16 ----------------------
// qb2 layout: [mt 4][kt 8][kq 8][row 256][8 bf16]  (LDS-tile order, pads 0)
__global__ void cvtq_kernel(const float* __restrict__ q, __bf16* __restrict__ qb){
  int g = blockIdx.x * 256 + threadIdx.x;
  int row = g >> 6;                 // 0..1023
  int k0 = (g & 63) * 8;
  float4 v0 = make_float4(0.f,0.f,0.f,0.f), v1 = v0;
  if(row < B_SZ){
    v0 = *(const float4*)(q + (size_t)row * D_SZ + k0);
    v1 = *(const float4*)(q + (size_t)row * D_SZ + k0 + 4);
  }
  bf16x8 w = { (__bf16)v0.x,(__bf16)v0.y,(__bf16)v0.z,(__bf16)v0.w,
               (__bf16)v1.x,(__bf16)v1.y,(__bf16)v1.z,(__bf16)v1.w };
  int mt = row >> 8, r = row & 255;
  int kt = k0 >> 6, kq = (k0 >> 3) & 7;
  *(bf16x8*)(qb + ((size_t)(mt*8 + kt)*8 + kq) * 2048 + (size_t)r * 8) = w;
}

// ---------------- rhs f32 [512][100000] -> rhsT2 tiled bf16 ----------------
// rhsT2 layout: [nt 391][kt 8][kq 8][row 256][8 bf16]
__global__ __launch_bounds__(256)
void tconv_kernel(const float* __restrict__ rhs, __bf16* __restrict__ rhsT){
  __shared__ float tile[64][65];
  const int tn = blockIdx.x;           // 0..1563
  const int tk = blockIdx.y;           // 0..7 (one k-tile per block)
  const int tid = threadIdx.x;
  const int n0 = tn * 64, k0 = tk * 64;
  // read phase: coalesced along n
  {
    const int nc = (tid & 15) * 4;
    const int kr0 = tid >> 4;          // 0..15
    #pragma unroll
    for(int i = 0; i < 4; i++){
      int kr = kr0 + i * 16;
      int n = n0 + nc;
      float4 v = (n < N_SZ) ? *(const float4*)(rhs + (size_t)(k0 + kr) * N_SZ + n)
                            : make_float4(0.f,0.f,0.f,0.f);
      tile[kr][nc+0] = v.x; tile[kr][nc+1] = v.y;
      tile[kr][nc+2] = v.z; tile[kr][nc+3] = v.w;
    }
  }
  __syncthreads();
  // write phase: lane = n (perfectly coalesced 1KB per kq region)
  {
    const int nl = tid & 63;
    const int kc = (tid >> 6) * 16;    // 0,16,32,48
    float a[16];
    #pragma unroll
    for(int j = 0; j < 16; j++) a[j] = tile[kc + j][nl];
    bf16x8 w0, w1;
    #pragma unroll
    for(int j = 0; j < 8; j++){ w0[j] = (__bf16)a[j]; w1[j] = (__bf16)a[8 + j]; }
    const int ng = n0 + nl;
    const int nt = ng >> 8, r = ng & 255;
    const int kq0 = kc >> 3;           // 0,2,4,6
    __bf16* dst = rhsT + ((size_t)(nt*8 + tk)*8 + kq0) * 2048 + (size_t)r * 8;
    *(bf16x8*)dst = w0;
    *(bf16x8*)(dst + 2048) = w1;       // kq0+1
  }
}

// ---------------- t[b] = q[b] . rhs[:, target[b]] (f32 exact) --------------
__global__ void t_kernel(const float* __restrict__ q, const float* __restrict__ rhs,
                         const int* __restrict__ target, float* __restrict__ t){
  int b = blockIdx.x;
  int tid = threadIdx.x;
  int tj = target[b];
  const float* qb = q + (size_t)b * D_SZ;
  float p = qb[tid] * rhs[(size_t)tid * N_SZ + tj]
          + qb[tid + 256] * rhs[(size_t)(tid + 256) * N_SZ + tj];
  for(int off = 32; off; off >>= 1) p += __shfl_down(p, off);
  __shared__ float red[4];
  if((tid & 63) == 0) red[tid >> 6] = p;
  __syncthreads();
  if(tid == 0) t[b] = red[0] + red[1] + red[2] + red[3];
}

// ---------------- dedupe filter∪target, bin into owning 256x256 tile -------
// Wave-parallel: shuffle-based first-occurrence test, no scratch arrays.
__global__ __launch_bounds__(64)
void prep_kernel(const int* __restrict__ filt, const int* __restrict__ target,
                 const float* __restrict__ t, int* __restrict__ cnt,
                 unsigned* __restrict__ entries, float* __restrict__ out){
  const int b = blockIdx.x;
  const int lane = threadIdx.x;      // 64 lanes, one wave
  int v = 0x7fffffff;
  if(lane < F_SZ) v = filt[b * F_SZ + lane];
  else if(lane == F_SZ) v = target[b];
  const bool active = lane <= F_SZ;
  bool first = active;
  #pragma unroll 1
  for(int k = 0; k < F_SZ; k++){     // lane>k duplicates of lane k are not-first
    int o = __shfl(v, k);
    if(active && k < lane && o == v) first = false;
  }
  if(first){
    int bid = (b >> 8) * NT_N2 + (v >> 8);
    int pos = atomicAdd(&cnt[bid], 1);
    if(pos < CAP2)
      entries[(size_t)bid * CAP2 + pos] = (unsigned)(((b & 255) << 8) | (v & 255));
  }
  int nuniq = (int)__popcll(__ballot(first));
  if(lane == 0){
    float tb = t[b];
    out[b] = 1.0f + ((NEGV >= tb) ? (float)nuniq : 0.0f);
  }
}

// ---------------- fused 256x256 MFMA GEMM + rank count (m201 8-phase) ------
// 8 waves (2M x 4N), per-wave 128x64 C (acc[8][4] f32x4). BK=64, 8 K-tiles.
// Per tile: 4 phases. Phase = {2-10 ds_read_b128 (operand regs, reused across
// phases) || stage ONE 16KB half-tile (2 gl_lds) || [counted vmcnt] ->
// ONE barrier -> setprio(1) 16 MFMA setprio(0)}.
// Staging units per tile kt (into buf kt+1&1): P0:A-h0 P1:B-h0 P2:A-h1 P3:B-h1
// (half = K-half, kq 0-3 vs 4-7 -> 16KB contiguous in the tiled layout).
// Certification (counted, never 0 mid-loop): vmcnt(4) at P1 certifies this
// tile's h1 units (read at P2/P3); vmcnt(4) at P3 certifies next tile's h0
// units (read at its P0/P1). Loads stay 2 units in flight across barriers.
// Tail: tile 7 stages nothing; its P1 uses vmcnt(0).
__global__ __launch_bounds__(512, 2)
void main_kernel(const __bf16* __restrict__ rhsT, const __bf16* __restrict__ qb,
                 const float* __restrict__ t, const int* __restrict__ cnt,
                 const unsigned* __restrict__ entries, float* __restrict__ out){
  // RING[buf][unit][8192]: unit 0=A-h0 1=B-h0 2=A-h1 3=B-h1 (16KB each)
  __shared__ __attribute__((aligned(16))) __bf16 RING[2][4][8192];  // 128 KB
  __shared__ float tl[256];
  __shared__ unsigned lent[CAP2];
  __shared__ unsigned bm[2048];      // 256x256 bitmap (8 KB)
  __shared__ int rowc[256];
  __shared__ int lcnt_s;

  // ---- bijective XCD swizzle (nwg=1564 = 8*195+4): 4 consecutive wg
  // (the 4 tile_b sharers of one B-strip) land on one XCD.
  const int h = blockIdx.x;
  const int xcd = h & 7, slot = h >> 3;
  const int wg = (xcd < 4 ? xcd * 196 : 784 + (xcd - 4) * 195) + slot;
  const int tile_n = wg >> 2;        // 0..390
  const int tile_b = wg & 3;         // 0..3
  const int bid = tile_b * NT_N2 + tile_n;
  const int tid = threadIdx.x;
  const int n0 = tile_n * BM2;
  const int b0 = tile_b * BM2;

  if(tid < 256){ int b = b0 + tid; tl[tid] = (b < B_SZ) ? t[b] : 0.f; rowc[tid] = 0; }
  if(tid < CAP2) lent[tid] = entries[(size_t)bid * CAP2 + tid];
  if(tid == 0){ int c = cnt[bid]; lcnt_s = (c > CAP2) ? CAP2 : c; }
  bm[tid] = 0; bm[tid + 512] = 0; bm[tid + 1024] = 0; bm[tid + 1536] = 0;

  const int wave = tid >> 6, lane = tid & 63;
  const int quad = lane >> 4, l15 = lane & 15;
  const int wm = wave >> 2, wn = wave & 3;   // 2 x 4 wave grid

  // loop-invariant LDS read indices (elements within a 8192-elem unit)
  const int idxA = quad * 2048 + (wm * 128 + l15) * 8;
  const int idxB = quad * 2048 + (wn * 64  + l15) * 8;

  // global staging pointers (linear: global layout == LDS layout)
  const __bf16* pAg = qb   + (size_t)tile_b * 131072 + (size_t)tid * 8;
  const __bf16* pBg = rhsT + (size_t)tile_n * 131072 + (size_t)tid * 8;

  f32x4 acc[8][4];
  #pragma unroll
  for(int i = 0; i < 8; i++)
    #pragma unroll
    for(int j = 0; j < 4; j++)
      acc[i][j] = (f32x4){0.f, 0.f, 0.f, 0.f};

  __syncthreads();                 // tables resident (drains vmcnt to 0)
  {                                // mark filter bitmap (LDS atomics)
    int lc = lcnt_s;
    if(tid < lc){
      unsigned en = lent[tid];
      unsigned row = en >> 8, col = en & 255;
      atomicOr(&bm[row * 8 + (col >> 5)], 1u << (col & 31));
    }
  }
  // ---- prologue: stage tile 0 (units 0..3) into buf 0; certify h0 only
  gl_lds16(pAg,         &RING[0][0][tid * 8]);
  gl_lds16(pAg + 4096,  &RING[0][0][4096 + tid * 8]);
  gl_lds16(pBg,         &RING[0][1][tid * 8]);
  gl_lds16(pBg + 4096,  &RING[0][1][4096 + tid * 8]);
  gl_lds16(pAg + 8192,  &RING[0][2][tid * 8]);
  gl_lds16(pAg + 12288, &RING[0][2][4096 + tid * 8]);
  gl_lds16(pBg + 8192,  &RING[0][3][tid * 8]);
  gl_lds16(pBg + 12288, &RING[0][3][4096 + tid * 8]);
  pAg += 16384; pBg += 16384;
  asm volatile("s_waitcnt vmcnt(4)" ::: "memory");   // units 0,1 resident
  __builtin_amdgcn_s_barrier();
  asm volatile("" ::: "memory");

  bf16x8 ar[8], br[2];

#define MFMA16(JA, JB) \
    __builtin_amdgcn_s_setprio(1); \
    _Pragma("unroll") \
    for(int i = 0; i < 8; i++){ \
      acc[i][JA] = __builtin_amdgcn_mfma_f32_16x16x32_bf16(ar[i], br[0], acc[i][JA], 0, 0, 0); \
      acc[i][JB] = __builtin_amdgcn_mfma_f32_16x16x32_bf16(ar[i], br[1], acc[i][JB], 0, 0, 0); \
    } \
    __builtin_amdgcn_s_setprio(0);

#define BARRIER_ { __builtin_amdgcn_s_barrier(); asm volatile("" ::: "memory"); }

#define TILE_BODY(CUR, NXT, STG, VM1STR) { \
    /* P0: reads A-h0(8)+B-h0 j01(2); stage A-h0(next) */ \
    _Pragma("unroll") \
    for(int k = 0; k < 8; k++) ar[k] = *(const bf16x8*)&RING[CUR][0][idxA + k * 128]; \
    br[0] = *(const bf16x8*)&RING[CUR][1][idxB]; \
    br[1] = *(const bf16x8*)&RING[CUR][1][idxB + 128]; \
    if(STG){ gl_lds16(pAg,        &RING[NXT][0][tid * 8]); \
             gl_lds16(pAg + 4096, &RING[NXT][0][4096 + tid * 8]); } \
    BARRIER_ \
    MFMA16(0, 1) \
    /* P1: reads B-h0 j23 (reuse ar); stage B-h0(next); certify h1 */ \
    br[0] = *(const bf16x8*)&RING[CUR][1][idxB + 256]; \
    br[1] = *(const bf16x8*)&RING[CUR][1][idxB + 384]; \
    if(STG){ gl_lds16(pBg,        &RING[NXT][1][tid * 8]); \
             gl_lds16(pBg + 4096, &RING[NXT][1][4096 + tid * 8]); } \
    asm volatile("s_waitcnt vmcnt(" VM1STR ")" ::: "memory"); \
    BARRIER_ \
    MFMA16(2, 3) \
    /* P2: reads A-h1(8)+B-h1 j01(2); stage A-h1(next) */ \
    _Pragma("unroll") \
    for(int k = 0; k < 8; k++) ar[k] = *(const bf16x8*)&RING[CUR][2][idxA + k * 128]; \
    br[0] = *(const bf16x8*)&RING[CUR][3][idxB]; \
    br[1] = *(const bf16x8*)&RING[CUR][3][idxB + 128]; \
    if(STG){ gl_lds16(pAg + 8192,  &RING[NXT][2][tid * 8]); \
             gl_lds16(pAg + 12288, &RING[NXT][2][4096 + tid * 8]); } \
    BARRIER_ \
    MFMA16(0, 1) \
    /* P3: reads B-h1 j23 (reuse ar); stage B-h1(next); certify next h0 */ \
    br[0] = *(const bf16x8*)&RING[CUR][3][idxB + 256]; \
    br[1] = *(const bf16x8*)&RING[CUR][3][idxB + 384]; \
    if(STG){ gl_lds16(pBg + 8192,  &RING[NXT][3][tid * 8]); \
             gl_lds16(pBg + 12288, &RING[NXT][3][4096 + tid * 8]); \
             asm volatile("s_waitcnt vmcnt(4)" ::: "memory"); \
             pAg += 16384; pBg += 16384; } \
    BARRIER_ \
    MFMA16(2, 3) \
  }

  #pragma unroll 1
  for(int kp = 0; kp < 4; kp++){
    TILE_BODY(0, 1, true, "4")                       // tiles 0,2,4,6
    if(kp < 3){ TILE_BODY(1, 0, true, "4") }         // tiles 1,3,5
    else      { TILE_BODY(1, 0, false, "0") }        // tile 7 (tail: drain)
  }
#undef TILE_BODY
#undef MFMA16
#undef BARRIER_

  // ---- epilogue: count s >= t_row, excluding bitmap-marked filter entries --
  // C/D layout: col = l15 (+16j), row = quad*4 + r (+16i) [verified mapping]
  #pragma unroll
  for(int i = 0; i < 8; i++){
    #pragma unroll
    for(int r = 0; r < 4; r++){
      const int row = wm*128 + i*16 + quad*4 + r;
      const float trow = tl[row];
      const unsigned w01 = bm[row * 8 + wn * 2];
      const unsigned w23 = bm[row * 8 + wn * 2 + 1];
      int c = 0;
      bool ge[4];
      #pragma unroll
      for(int j = 0; j < 4; j++){
        int ncol = n0 + wn*64 + j*16 + l15;
        ge[j] = (ncol < N_SZ) && (acc[i][j][r] >= trow);
        c += ge[j] ? 1 : 0;
      }
      if(w01 | w23){                      // rare
        #pragma unroll
        for(int j = 0; j < 4; j++){
          unsigned w = (j < 2) ? w01 : w23;
          if(((w >> ((j & 1) * 16 + l15)) & 1u) && ge[j]) c--;
        }
      }
      c += __shfl_xor(c, 1);
      c += __shfl_xor(c, 2);
      c += __shfl_xor(c, 4);
      c += __shfl_xor(c, 8);
      if(l15 == 0) atomicAdd(&rowc[row], c);
    }
  }
  __syncthreads();
  if(tid < 256){
    int bg = b0 + tid, c = rowc[tid];
    if(bg < B_SZ && c) atomicAdd(&out[bg], (float)c);
  }
}

// ---------------- correctness fallback (small ws): plain f32 counting ------
__global__ __launch_bounds__(256)
void fallback_kernel(const float* __restrict__ q, const float* __restrict__ rhs,
                     const int* __restrict__ filt, const int* __restrict__ target,
                     const float* __restrict__ t, float* __restrict__ out){
  const int b = blockIdx.x;
  const int tid = threadIdx.x;
  __shared__ float qs[D_SZ];
  __shared__ int fs[F_SZ + 1];
  __shared__ float tbs;
  qs[tid] = q[(size_t)b * D_SZ + tid];
  qs[tid + 256] = q[(size_t)b * D_SZ + tid + 256];
  if(tid < F_SZ) fs[tid] = filt[b * F_SZ + tid];
  if(tid == F_SZ) fs[tid] = target[b];
  if(tid == 0) tbs = t[b];
  __syncthreads();
  const float tb = tbs;
  int c = 0;
  const int nend = (blockIdx.y + 1) * 2048 < N_SZ ? (blockIdx.y + 1) * 2048 : N_SZ;
  for(int n = blockIdx.y * 2048 + tid; n < nend; n += 256){
    float s = 0.f;
    for(int k = 0; k < D_SZ; k++) s += qs[k] * rhs[(size_t)k * N_SZ + n];
    if(s >= tb){
      bool m = false;
      for(int i = 0; i <= F_SZ; i++) if(fs[i] == n){ m = true; break; }
      if(!m) c++;
    }
  }
  for(int off = 32; off; off >>= 1) c += __shfl_down(c, off);
  __shared__ int red[4];
  if((tid & 63) == 0) red[tid >> 6] = c;
  __syncthreads();
  if(tid == 0){
    int s = red[0] + red[1] + red[2] + red[3];
    if(s) atomicAdd(&out[b], (float)s);
  }
}

extern "C" void kernel_launch(void* const* d_in, const int* in_sizes, int n_in,
                              void* d_out, int out_size, void* d_ws, size_t ws_size,
                              hipStream_t stream){
  const float* q    = (const float*)d_in[0];
  const float* rhs  = (const float*)d_in[1];
  const int* filt   = (const int*)d_in[2];
  const int* target = (const int*)d_in[3];
  float* out = (float*)d_out;
  char* ws = (char*)d_ws;
  float* t          = (float*)(ws + T_OFF);
  int* cnt          = (int*)(ws + CNT_OFF);
  unsigned* entries = (unsigned*)(ws + ENT_OFF);
  __bf16* qb        = (__bf16*)(ws + QB_OFF);
  __bf16* rhsT      = (__bf16*)(ws + RT_OFF);

  const size_t need = (size_t)RT_OFF + (size_t)RT_ROWS * D_SZ * 2;   // ~106.7 MB
  const bool big = ws_size >= need;

  zero_ws<<<32, 256, 0, stream>>>((int*)ws);
  t_kernel<<<B_SZ, 256, 0, stream>>>(q, rhs, target, t);
  prep_kernel<<<B_SZ, 64, 0, stream>>>(filt, target, t, cnt, entries, out);
  if(big){
    cvtq_kernel<<<256, 256, 0, stream>>>(q, qb);
    tconv_kernel<<<dim3(RT_ROWS / 64, 8), 256, 0, stream>>>(rhs, rhsT);
    main_kernel<<<G2, 512, 0, stream>>>(rhsT, qb, t, cnt, entries, out);
  } else {
    fallback_kernel<<<dim3(B_SZ, 49), 256, 0, stream>>>(q, rhs, filt, target, t, out);
  }
}

// Round 8
// 453.624 us; speedup vs baseline: 3.0304x; 1.8563x over previous
//
#include <hip/hip_runtime.h>
#include <hip/hip_bf16.h>
#include <cstdint>

#define B_SZ 1000
#define D_SZ 512
#define N_SZ 100000
#define F_SZ 50
#define NEGV -1000000.0f

// ---- 128x256 main tile geometry (2 blocks/CU) ----
#define BMr 128              // b-rows per tile
#define BNc 256              // n-cols per tile
#define NT_N3 391            // 391*256 = 100096
#define NT_B3 8              // 1024/128
#define G3 (NT_B3 * NT_N3)   // 3128 blocks (divisible by 8 XCDs)
#define CAP3 96              // avg entries/bin ~16.3

#define T_OFF 0
#define CNT_OFF 4096             // cnt: 3128 ints = 12.5 KB (zero_ws covers 32KB)
#define ENT_OFF 32768            // entries: 3128*96*4B = 1.20 MB (< 2MB gap)
#define QB_OFF  0x200000         // qb3: 8*16*4*128*16B = 1 MB (2 MB region)
#define RT_OFF  0x400000         // rhsT3: 391*16*4*256*16B = 102.5 MB
#define RT_ROWS 100096

typedef __bf16 bf16x8 __attribute__((ext_vector_type(8)));
typedef float f32x4 __attribute__((ext_vector_type(4)));

__device__ __forceinline__ void gl_lds16(const void* g, void* l){
  __builtin_amdgcn_global_load_lds(
      (const __attribute__((address_space(1))) unsigned int*)g,
      (__attribute__((address_space(3))) unsigned int*)l, 16, 0, 0);
}

// ---------------- zero t/cnt regions (ws poisoned 0xAA each call) ----------
__global__ void zero_ws(int* p){ p[blockIdx.x * 256 + threadIdx.x] = 0; }

// ---------------- q f32 [1000][512] -> qb3 tiled bf16 ----------------------
// qb3 layout: [mt 8][kt 16][kq 4][row 128][8 bf16]  (pads 0)
__global__ void cvtq_kernel(const float* __restrict__ q, __bf16* __restrict__ qb){
  int g = blockIdx.x * 256 + threadIdx.x;
  int row = g >> 6;                 // 0..1023
  int k0 = (g & 63) * 8;
  float4 v0 = make_float4(0.f,0.f,0.f,0.f), v1 = v0;
  if(row < B_SZ){
    v0 = *(const float4*)(q + (size_t)row * D_SZ + k0);
    v1 = *(const float4*)(q + (size_t)row * D_SZ + k0 + 4);
  }
  bf16x8 w = { (__bf16)v0.x,(__bf16)v0.y,(__bf16)v0.z,(__bf16)v0.w,
               (__bf16)v1.x,(__bf16)v1.y,(__bf16)v1.z,(__bf16)v1.w };
  int mt = row >> 7, r = row & 127;
  int kt = k0 >> 5, kq = (k0 >> 3) & 3;
  *(bf16x8*)(qb + ((size_t)(mt*16 + kt)*4 + kq) * 1024 + (size_t)r * 8) = w;
}

// ---------------- rhs f32 [512][100000] -> rhsT3 tiled bf16 ----------------
// rhsT3 layout: [nt 391][kt 16][kq 4][row 256][8 bf16]
__global__ __launch_bounds__(256)
void tconv_kernel(const float* __restrict__ rhs, __bf16* __restrict__ rhsT){
  __shared__ float tile[64][65];
  const int tn = blockIdx.x;           // 0..1563
  const int tk = blockIdx.y;           // 0..7 (64 k's per block)
  const int tid = threadIdx.x;
  const int n0 = tn * 64, k0 = tk * 64;
  // read phase: coalesced along n
  {
    const int nc = (tid & 15) * 4;
    const int kr0 = tid >> 4;          // 0..15
    #pragma unroll
    for(int i = 0; i < 4; i++){
      int kr = kr0 + i * 16;
      int n = n0 + nc;
      float4 v = (n < N_SZ) ? *(const float4*)(rhs + (size_t)(k0 + kr) * N_SZ + n)
                            : make_float4(0.f,0.f,0.f,0.f);
      tile[kr][nc+0] = v.x; tile[kr][nc+1] = v.y;
      tile[kr][nc+2] = v.z; tile[kr][nc+3] = v.w;
    }
  }
  __syncthreads();
  // write phase: lane = n (coalesced 1KB per kq region)
  {
    const int nl = tid & 63;
    const int kc = (tid >> 6) * 16;    // 0,16,32,48
    float a[16];
    #pragma unroll
    for(int j = 0; j < 16; j++) a[j] = tile[kc + j][nl];
    bf16x8 w0, w1;
    #pragma unroll
    for(int j = 0; j < 8; j++){ w0[j] = (__bf16)a[j]; w1[j] = (__bf16)a[8 + j]; }
    const int ng = n0 + nl;
    const int nt = ng >> 8, r = ng & 255;
    const int kg = k0 + kc;            // multiple of 16
    const int kt = kg >> 5, kq0 = (kg >> 3) & 3;   // kq0 in {0,2}
    __bf16* dst = rhsT + ((size_t)(nt*16 + kt)*4 + kq0) * 2048 + (size_t)r * 8;
    *(bf16x8*)dst = w0;
    *(bf16x8*)(dst + 2048) = w1;       // kq0+1
  }
}

// ---------------- t[b] = q[b] . rhs[:, target[b]] (f32 exact) --------------
__global__ void t_kernel(const float* __restrict__ q, const float* __restrict__ rhs,
                         const int* __restrict__ target, float* __restrict__ t){
  int b = blockIdx.x;
  int tid = threadIdx.x;
  int tj = target[b];
  const float* qb = q + (size_t)b * D_SZ;
  float p = qb[tid] * rhs[(size_t)tid * N_SZ + tj]
          + qb[tid + 256] * rhs[(size_t)(tid + 256) * N_SZ + tj];
  for(int off = 32; off; off >>= 1) p += __shfl_down(p, off);
  __shared__ float red[4];
  if((tid & 63) == 0) red[tid >> 6] = p;
  __syncthreads();
  if(tid == 0) t[b] = red[0] + red[1] + red[2] + red[3];
}

// ---------------- dedupe filter∪target, bin into owning 128x256 tile -------
// Wave-parallel: shuffle-based first-occurrence test, no scratch arrays.
__global__ __launch_bounds__(64)
void prep_kernel(const int* __restrict__ filt, const int* __restrict__ target,
                 const float* __restrict__ t, int* __restrict__ cnt,
                 unsigned* __restrict__ entries, float* __restrict__ out){
  const int b = blockIdx.x;
  const int lane = threadIdx.x;      // 64 lanes, one wave
  int v = 0x7fffffff;
  if(lane < F_SZ) v = filt[b * F_SZ + lane];
  else if(lane == F_SZ) v = target[b];
  const bool active = lane <= F_SZ;
  bool first = active;
  #pragma unroll 1
  for(int k = 0; k < F_SZ; k++){     // lane>k duplicates of lane k are not-first
    int o = __shfl(v, k);
    if(active && k < lane && o == v) first = false;
  }
  if(first){
    int bid = (b >> 7) * NT_N3 + (v >> 8);
    int pos = atomicAdd(&cnt[bid], 1);
    if(pos < CAP3)
      entries[(size_t)bid * CAP3 + pos] = (unsigned)(((b & 127) << 8) | (v & 255));
  }
  int nuniq = (int)__popcll(__ballot(first));
  if(lane == 0){
    float tb = t[b];
    out[b] = 1.0f + ((NEGV >= tb) ? (float)nuniq : 0.0f);
  }
}

// ---------------- fused 128x256 MFMA GEMM + rank count ---------------------
// 8 waves (2M x 4N), per-wave 64x64 C (acc[4][4] f32x4 = 64 regs). BK=32,
// 16 K-tiles. Monolithic 2-barrier loop (R2 structure, the best-measured),
// counted vmcnt(3). LDS: 2x(8KB A + 16KB B) + ~7KB tables ~= 55KB ->
// 2 BLOCKS/CU. Theory (R7 post-mortem): at 1 block/CU, barrier-locked waves
// alternate LDS-read and MFMA phases coherently (pipe alternation explains
// the schedule-invariant ~24% MfmaUtil). Two independent blocks drift freely
// and fill each other's idle pipe (m114). acc=64 keeps 4 waves/SIMD without
// the R6/R7 spill (WRITE_SIZE is the tripwire).
__global__ __launch_bounds__(512, 4)
void main_kernel(const __bf16* __restrict__ rhsT, const __bf16* __restrict__ qb,
                 const float* __restrict__ t, const int* __restrict__ cnt,
                 const unsigned* __restrict__ entries, float* __restrict__ out){
  __shared__ __attribute__((aligned(16))) __bf16 A2[2][4096];  // 2x8 KB
  __shared__ __attribute__((aligned(16))) __bf16 B2[2][8192];  // 2x16 KB
  __shared__ float tl[128];
  __shared__ unsigned lent[CAP3];
  __shared__ unsigned bm[1024];      // 128 rows x 256 cols bitmap (4 KB)
  __shared__ int rowc[128];
  __shared__ int lcnt_s;

  // ---- XCD swizzle: nwg=3128=8*391. XCD x owns wg [x*391,(x+1)*391);
  // consecutive wg share tile_n (8 tile_b sharers adjacent on one XCD).
  const int h = blockIdx.x;
  const int wg = (h & 7) * 391 + (h >> 3);
  const int tile_n = wg >> 3;        // 0..390
  const int tile_b = wg & 7;         // 0..7
  const int bid = tile_b * NT_N3 + tile_n;
  const int tid = threadIdx.x;
  const int n0 = tile_n * BNc;
  const int b0 = tile_b * BMr;

  if(tid < 128){ int b = b0 + tid; tl[tid] = (b < B_SZ) ? t[b] : 0.f; rowc[tid] = 0; }
  if(tid < CAP3) lent[tid] = entries[(size_t)bid * CAP3 + tid];
  if(tid == 0){ int c = cnt[bid]; lcnt_s = (c > CAP3) ? CAP3 : c; }
  if(tid < 512){ bm[tid & 1023] = 0; if(tid < 512) bm[(tid + 512) & 1023] = 0; }

  const int wave = tid >> 6, lane = tid & 63;
  const int quad = lane >> 4, l15 = lane & 15;
  const int wm = wave >> 2, wn = wave & 3;   // 2 x 4 wave grid

  // loop-invariant LDS frag indices (elements)
  const int idxA = quad * 1024 + (wm * 64 + l15) * 8;
  const int idxB = quad * 2048 + (wn * 64 + l15) * 8;

  // global staging pointers (linear: global layout == LDS layout)
  // per K-tile: A 4096 elems (1 load/thread), B 8192 elems (2 loads/thread)
  const __bf16* pAg = qb   + (size_t)tile_b * 65536  + (size_t)tid * 8;
  const __bf16* pBg = rhsT + (size_t)tile_n * 131072 + (size_t)tid * 8;

  f32x4 acc[4][4];
  #pragma unroll
  for(int i = 0; i < 4; i++)
    #pragma unroll
    for(int j = 0; j < 4; j++)
      acc[i][j] = (f32x4){0.f, 0.f, 0.f, 0.f};

  __syncthreads();                 // tables resident (drains vmcnt to 0)
  {                                // mark filter bitmap (LDS atomics)
    int lc = lcnt_s;
    if(tid < lc){
      unsigned en = lent[tid];
      unsigned row = en >> 8, col = en & 255;
      atomicOr(&bm[row * 8 + (col >> 5)], 1u << (col & 31));
    }
  }
  // ---- prologue: stage K-tile 0 into buffer 0 (3 loads/thread)
  gl_lds16(pAg,        &A2[0][tid * 8]);
  gl_lds16(pBg,        &B2[0][tid * 8]);
  gl_lds16(pBg + 4096, &B2[0][4096 + tid * 8]);
  pAg += 4096; pBg += 8192;
  asm volatile("s_waitcnt vmcnt(0)" ::: "memory");
  __builtin_amdgcn_s_barrier();
  asm volatile("" ::: "memory");

  #pragma unroll 1
  for(int kt = 0; kt < 16; kt++){
    const int cur = kt & 1, nxt = cur ^ 1;
    if(kt < 15){
      // issue next tile's 3 loads; vmcnt(3) drains only tile kt's loads
      gl_lds16(pAg,        &A2[nxt][tid * 8]);
      gl_lds16(pBg,        &B2[nxt][tid * 8]);
      gl_lds16(pBg + 4096, &B2[nxt][4096 + tid * 8]);
      pAg += 4096; pBg += 8192;
      asm volatile("s_waitcnt vmcnt(3)" ::: "memory");
    } else {
      asm volatile("s_waitcnt vmcnt(0)" ::: "memory");
    }
    __builtin_amdgcn_s_barrier();        // tile kt resident for all waves
    asm volatile("" ::: "memory");

    bf16x8 a4[4], b4[4];
    #pragma unroll
    for(int i = 0; i < 4; i++) a4[i] = *(const bf16x8*)&A2[cur][idxA + i * 128];
    #pragma unroll
    for(int j = 0; j < 4; j++) b4[j] = *(const bf16x8*)&B2[cur][idxB + j * 128];
    __builtin_amdgcn_s_setprio(1);
    #pragma unroll
    for(int i = 0; i < 4; i++)
      #pragma unroll
      for(int j = 0; j < 4; j++)
        acc[i][j] = __builtin_amdgcn_mfma_f32_16x16x32_bf16(a4[i], b4[j], acc[i][j], 0, 0, 0);
    __builtin_amdgcn_s_setprio(0);

    asm volatile("s_waitcnt lgkmcnt(0)" ::: "memory");  // reads of buf[cur] done
    __builtin_amdgcn_s_barrier();
    asm volatile("" ::: "memory");
  }

  // ---- epilogue: count s >= t_row, excluding bitmap-marked filter entries --
  // C/D layout: col = l15 (+16j), row = quad*4 + r (+16i) [verified mapping]
  #pragma unroll
  for(int i = 0; i < 4; i++){
    #pragma unroll
    for(int r = 0; r < 4; r++){
      const int row = wm*64 + i*16 + quad*4 + r;
      const float trow = tl[row];
      const unsigned w01 = bm[row * 8 + wn * 2];
      const unsigned w23 = bm[row * 8 + wn * 2 + 1];
      int c = 0;
      bool ge[4];
      #pragma unroll
      for(int j = 0; j < 4; j++){
        int ncol = n0 + wn*64 + j*16 + l15;
        ge[j] = (ncol < N_SZ) && (acc[i][j][r] >= trow);
        c += ge[j] ? 1 : 0;
      }
      if(w01 | w23){                      // rare
        #pragma unroll
        for(int j = 0; j < 4; j++){
          unsigned w = (j < 2) ? w01 : w23;
          if(((w >> ((j & 1) * 16 + l15)) & 1u) && ge[j]) c--;
        }
      }
      c += __shfl_xor(c, 1);
      c += __shfl_xor(c, 2);
      c += __shfl_xor(c, 4);
      c += __shfl_xor(c, 8);
      if(l15 == 0) atomicAdd(&rowc[row], c);
    }
  }
  __syncthreads();
  if(tid < 128){
    int bg = b0 + tid, c = rowc[tid];
    if(bg < B_SZ && c) atomicAdd(&out[bg], (float)c);
  }
}

// ---------------- correctness fallback (small ws): plain f32 counting ------
__global__ __launch_bounds__(256)
void fallback_kernel(const float* __restrict__ q, const float* __restrict__ rhs,
                     const int* __restrict__ filt, const int* __restrict__ target,
                     const float* __restrict__ t, float* __restrict__ out){
  const int b = blockIdx.x;
  const int tid = threadIdx.x;
  __shared__ float qs[D_SZ];
  __shared__ int fs[F_SZ + 1];
  __shared__ float tbs;
  qs[tid] = q[(size_t)b * D_SZ + tid];
  qs[tid + 256] = q[(size_t)b * D_SZ + tid + 256];
  if(tid < F_SZ) fs[tid] = filt[b * F_SZ + tid];
  if(tid == F_SZ) fs[tid] = target[b];
  if(tid == 0) tbs = t[b];
  __syncthreads();
  const float tb = tbs;
  int c = 0;
  const int nend = (blockIdx.y + 1) * 2048 < N_SZ ? (blockIdx.y + 1) * 2048 : N_SZ;
  for(int n = blockIdx.y * 2048 + tid; n < nend; n += 256){
    float s = 0.f;
    for(int k = 0; k < D_SZ; k++) s += qs[k] * rhs[(size_t)k * N_SZ + n];
    if(s >= tb){
      bool m = false;
      for(int i = 0; i <= F_SZ; i++) if(fs[i] == n){ m = true; break; }
      if(!m) c++;
    }
  }
  for(int off = 32; off; off >>= 1) c += __shfl_down(c, off);
  __shared__ int red[4];
  if((tid & 63) == 0) red[tid >> 6] = c;
  __syncthreads();
  if(tid == 0){
    int s = red[0] + red[1] + red[2] + red[3];
    if(s) atomicAdd(&out[b], (float)s);
  }
}

extern "C" void kernel_launch(void* const* d_in, const int* in_sizes, int n_in,
                              void* d_out, int out_size, void* d_ws, size_t ws_size,
                              hipStream_t stream){
  const float* q    = (const float*)d_in[0];
  const float* rhs  = (const float*)d_in[1];
  const int* filt   = (const int*)d_in[2];
  const int* target = (const int*)d_in[3];
  float* out = (float*)d_out;
  char* ws = (char*)d_ws;
  float* t          = (float*)(ws + T_OFF);
  int* cnt          = (int*)(ws + CNT_OFF);
  unsigned* entries = (unsigned*)(ws + ENT_OFF);
  __bf16* qb        = (__bf16*)(ws + QB_OFF);
  __bf16* rhsT      = (__bf16*)(ws + RT_OFF);

  const size_t need = (size_t)RT_OFF + (size_t)RT_ROWS * D_SZ * 2;   // ~106.7 MB
  const bool big = ws_size >= need;

  zero_ws<<<32, 256, 0, stream>>>((int*)ws);
  t_kernel<<<B_SZ, 256, 0, stream>>>(q, rhs, target, t);
  prep_kernel<<<B_SZ, 64, 0, stream>>>(filt, target, t, cnt, entries, out);
  if(big){
    cvtq_kernel<<<256, 256, 0, stream>>>(q, qb);
    tconv_kernel<<<dim3(RT_ROWS / 64, 8), 256, 0, stream>>>(rhs, rhsT);
    main_kernel<<<G3, 512, 0, stream>>>(rhsT, qb, t, cnt, entries, out);
  } else {
    fallback_kernel<<<dim3(B_SZ, 49), 256, 0, stream>>>(q, rhs, filt, target, t, out);
  }
}